// Round 3
// baseline (134.992 us; speedup 1.0000x reference)
//
#include <hip/hip_runtime.h>

#define TAU_F      0.1f
#define OMT_F      0.9f           // 1 - TAU
#define N_ITERS    1000
#define EPS_F      1e-8f
#define LOG2E_F    1.44269504088896340736f

// Swap value with adjacent lane (xor 1) via DPP quad_perm [1,0,3,2].
__device__ __forceinline__ float swap_adj(float x){
  int xi = __builtin_bit_cast(int, x);
  int rr = __builtin_amdgcn_update_dpp(xi, xi, 0xB1, 0xF, 0xF, false);
  return __builtin_bit_cast(float, rr);
}

// Thread t: row r = t>>1, player p = t&1 (0 = u/maximizer, 1 = v/minimizer).
// Pe has row 1 and column 1 identically zero -> z1 == 0, o1 never consumed.
//
// State carried: scaled scores z = A·o (A = per-lane sign-folded, lambda-scaled
// payoff matrix over rows/cols {0,2,3}) and d = z2 - z3. Since the opponent's
// strategy update is o' = 0.9·o + 0.1·b_opp and b_opp = e0 + b1o·(-1,p2o,p3o):
//   z'_c = fma(b1o, h_c, n_c),  n_c = fma(0.9, z_c, K_c)   [off critical path]
//   K_c  = 0.1·A_c0 (constant), h_c = -K_c + 0.1·A_c2·p2o + 0.1·A_c3·p3o
// p2o/p3o are ready well before b1 (swapped early), so only ONE fma sits
// between the opponent's b1 and the next iteration's inner exp2.
__global__ __launch_bounds__(64, 1) void soccer_kernel(
    const float* __restrict__ x, const float* __restrict__ W,
    const float* __restrict__ P, float* __restrict__ out, int N)
{
  const int t = blockIdx.x * 64 + threadIdx.x;
  const int r = t >> 1;
  const int p = t & 1;
  if (r >= N) return;

  const float xv = x[r];
  const float w0 = W[2 * p + 0], w1 = W[2 * p + 1];
  const float l0 = __builtin_amdgcn_exp2f(xv * (w0 * LOG2E_F)) + EPS_F;
  const float l1 = __builtin_amdgcn_exp2f(xv * (w1 * LOG2E_F)) + EPS_F;

  const float kappa = l0 * LOG2E_F;   // scale row 0
  const float cin   = l1 * LOG2E_F;   // scale rows 2,3
  const float rho   = l0 / l1;

  // K_c = TAU*scaled A_c0 ; B_cj = TAU*scaled A_cj  (cols {0,2,3} only).
  float K0, K2, K3, B02, B03, B22, B23, B32, B33;
  {
    auto m = [&](int c, int k) -> float {
      const float pu = P[c * 4 + k];
      const float pv = -P[k * 4 + c];
      return (p == 0) ? pu : pv;
    };
    const float tk = TAU_F * kappa, tc = TAU_F * cin;
    K0 = tk * m(0,0); B02 = tk * m(0,2); B03 = tk * m(0,3);
    K2 = tc * m(2,0); B22 = tc * m(2,2); B23 = tc * m(2,3);
    K3 = tc * m(3,0); B32 = tc * m(3,2); B33 = tc * m(3,3);
  }

  // z_init = A·(0.5, 0.25, 0.25) = 5*K + 2.5*(B2 + B3)
  float z0 = 5.0f * K0 + 2.5f * (B02 + B03);
  float z2 = 5.0f * K2 + 2.5f * (B22 + B23);
  float z3 = 5.0f * K3 + 2.5f * (B32 + B33);
  float d  = z2 - z3;

  float y0 = 0.5f, y1 = 0.5f, y2 = 0.25f, y3 = 0.25f;

#pragma unroll 4
  for (int it = 0; it < N_ITERS; ++it) {
    // ---- critical head: inner lse + outer sigmoid (4 transcendentals) ----
    const float e  = __builtin_amdgcn_exp2f(-__builtin_fabsf(d)); // 2^(mn-mx), -|d| folds to src mods
    const float s  = 1.0f + e;
    const float rs = __builtin_amdgcn_rcpf(s);    // parallel with log
    const float lg = __builtin_amdgcn_logf(s);    // log2(1+e)
    const float mx = fmaxf(z2, z3);               // off-path (feeds base)
    const float plo = e * rs;
    const bool  c23 = (d >= 0.0f);
    const float p2 = c23 ? rs  : plo;
    const float p3 = c23 ? plo : rs;
    const float base = fmaf(-rho, mx, z0);        // off exp/log path
    const float t2   = fmaf(-rho, lg, base);
    const float e2   = __builtin_amdgcn_exp2f(t2);
    const float b1   = __builtin_amdgcn_rcpf(1.0f + e2); // inf-safe: rcp(inf)=0

    // ---- early swaps + off-path prep for the blend ----
    const float p2o = swap_adj(p2);
    const float p3o = swap_adj(p3);
    const float h0 = fmaf(B02, p2o, fmaf(B03, p3o, -K0));
    const float h2 = fmaf(B22, p2o, fmaf(B23, p3o, -K2));
    const float h3 = fmaf(B32, p2o, fmaf(B33, p3o, -K3));
    const float n0 = fmaf(OMT_F, z0, K0);
    const float n2 = fmaf(OMT_F, z2, K2);
    const float n3 = fmaf(OMT_F, z3, K3);
    const float dh = h2 - h3;
    const float dn = n2 - n3;

    const float b1o = swap_adj(b1);               // ON critical path

    // ---- one fma from b1o to next iteration's state ----
    d  = fmaf(b1o, dh, dn);                       // = z2' - z3'
    z0 = fmaf(b1o, h0, n0);
    z2 = fmaf(b1o, h2, n2);
    z3 = fmaf(b1o, h3, n3);

    // ---- y accumulators (output only, own b; fully off-path) ----
    y0 = fmaf(-TAU_F, b1, fmaf(OMT_F, y0, TAU_F));
    y1 = fmaf( TAU_F, b1, OMT_F * y1);
    y2 = fmaf( TAU_F, b1 * p2, OMT_F * y2);
    y3 = fmaf( TAU_F, b1 * p3, OMT_F * y3);
  }

  // Output layout: [ u : N*4 | v : N*4 | j : N*4 ], all fp32.
  float4* uv = (float4*)out;
  uv[(size_t)p * N + r] = make_float4(y0, y1, y2, y3);
  float2* jj = (float2*)(out + (size_t)8 * N);
  jj[t] = make_float2(l0, l1);
}

extern "C" void kernel_launch(void* const* d_in, const int* in_sizes, int n_in,
                              void* d_out, int out_size, void* d_ws, size_t ws_size,
                              hipStream_t stream) {
  const float* x = (const float*)d_in[0];
  const float* W = (const float*)d_in[1];
  const float* P = (const float*)d_in[2];
  float* out = (float*)d_out;
  const int N = in_sizes[0];          // 8192 rows
  const int threads = 2 * N;          // 2 lanes per row
  dim3 block(64);                     // 1 wave per block -> spread across all 256 CUs
  dim3 grid((threads + 63) / 64);
  hipLaunchKernelGGL(soccer_kernel, grid, block, 0, stream, x, W, P, out, N);
}

// Round 4
// 114.546 us; speedup vs baseline: 1.1785x; 1.1785x over previous
//
#include <hip/hip_runtime.h>

#define TAU_F      0.1f
#define OMT_F      0.9f           // 1 - TAU
#define N_ITERS    1000
#define EPS_F      1e-8f
#define LOG2E_F    1.44269504088896340736f

__device__ __forceinline__ float fexp2(float x){ return __builtin_amdgcn_exp2f(x); }
__device__ __forceinline__ float flog2(float x){ return __builtin_amdgcn_logf(x); }
__device__ __forceinline__ float frcp (float x){ return __builtin_amdgcn_rcpf(x); }

// Swap value with adjacent lane (xor 1) via DPP quad_perm [1,0,3,2].
__device__ __forceinline__ float swap_adj(float x){
  int xi = __builtin_bit_cast(int, x);
  int rr = __builtin_amdgcn_update_dpp(xi, xi, 0xB1, 0xF, 0xF, false);
  return __builtin_bit_cast(float, rr);
}

// Thread t: row r = t>>1, player p = t&1 (0 = u/maximizer, 1 = v/minimizer).
//
// Model: solo wave per CU -> wall time = issue cadence (~4.4 cyc/instr) x
// instruction count. Minimize VALU instructions per iteration (target 25):
//  - Invariants y0+y1=1, y2+y3=y1 (exactly preserved by the QRE-FP update)
//    -> carry only y1,y2; opponent strategy needs only o1,o2 (2 DPP swaps).
//  - Fold o0=1-o1, o3=o1-o2 into the payoff matvec:
//      z_c = K_c + C_c1*o1 + C_c2*o2   (2 fma per row; rows 0,2 + differenced
//      row d=z2-z3). mx = z2 - min(d,0).
//  - Scaled log2 domain (as before): z~0 = l0*log2e*z0, z~23 = l1*log2e*z23,
//      b1 = rcp(1+exp2(z~0 - rho*(mx+log2(1+2^-|d|)))),  rho = l0/l1.
//  - p2 = rcp(1+exp2(-d)) directly (overflow-safe: rcp(inf)=0) — no selects.
__global__ __launch_bounds__(64, 1) void soccer_kernel(
    const float* __restrict__ x, const float* __restrict__ W,
    const float* __restrict__ P, float* __restrict__ out, int N)
{
  const int t = blockIdx.x * 64 + threadIdx.x;
  const int r = t >> 1;
  const int p = t & 1;
  if (r >= N) return;

  const float xv = x[r];
  const float w0 = W[2 * p + 0], w1 = W[2 * p + 1];
  const float l0 = fexp2(xv * (w0 * LOG2E_F)) + EPS_F;
  const float l1 = fexp2(xv * (w1 * LOG2E_F)) + EPS_F;

  const float kappa = l0 * LOG2E_F;   // scale row 0
  const float cin   = l1 * LOG2E_F;   // scale rows 2,3
  const float rho   = l0 / l1;

  // Per-lane sign-folded scaled payoff A over rows/cols {0,2,3}
  // (Pe row 1 / col 1 are identically zero), then fold o0=1-o1, o3=o1-o2:
  //   z_c = K_c + C_c1*o1 + C_c2*o2,  K_c=A_c0, C_c1=A_c3-A_c0, C_c2=A_c2-A_c3.
  float K0, C01, C02, K2, C21, C22, dK, dC1, dC2;
  {
    auto m = [&](int c, int k) -> float {
      const float pu = P[c * 4 + k];
      const float pv = -P[k * 4 + c];
      return (p == 0) ? pu : pv;
    };
    const float A00 = kappa * m(0,0), A02 = kappa * m(0,2), A03 = kappa * m(0,3);
    const float A20 = cin   * m(2,0), A22 = cin   * m(2,2), A23 = cin   * m(2,3);
    const float A30 = cin   * m(3,0), A32 = cin   * m(3,2), A33 = cin   * m(3,3);
    K0 = A00; C01 = A03 - A00; C02 = A02 - A03;
    K2 = A20; C21 = A23 - A20; C22 = A22 - A23;
    const float K3 = A30, C31 = A33 - A30, C32 = A32 - A33;
    dK = K2 - K3; dC1 = C21 - C31; dC2 = C22 - C32;
  }

  float y1 = 0.5f, y2 = 0.25f;   // y0 = 1-y1, y3 = y1-y2 (exact invariants)

#pragma unroll 8
  for (int it = 0; it < N_ITERS; ++it) {
    const float o1 = swap_adj(y1);                    // opponent y1
    const float o2 = swap_adj(y2);                    // opponent y2

    const float z0 = fmaf(C02, o2, fmaf(C01, o1, K0));
    const float z2 = fmaf(C22, o2, fmaf(C21, o1, K2));
    const float d  = fmaf(dC2, o2, fmaf(dC1, o1, dK)); // z~2 - z~3
    const float mx = z2 - fminf(d, 0.0f);              // max(z~2, z~3)

    // Inner lse (safe |d| form) + outer sigmoid.
    const float e    = fexp2(-__builtin_fabsf(d));     // (0,1]
    const float s    = 1.0f + e;
    const float lg   = flog2(s);
    const float base = fmaf(-rho, mx, z0);             // off trans path
    const float t2   = fmaf(-rho, lg, base);
    const float e2   = fexp2(t2);
    const float b1   = frcp(1.0f + e2);                // rcp(inf)=0: safe

    // p2 = softmax(z~2,z~3)[0] as a direct sigmoid (overflow-safe).
    const float ep = fexp2(-d);
    const float p2 = frcp(1.0f + ep);

    // y' = 0.9 y + 0.1 b  (only the carried pair).
    const float tb = TAU_F * b1;
    y1 = fmaf(OMT_F, y1, tb);
    const float q  = tb * p2;
    y2 = fmaf(OMT_F, y2, q);
  }

  const float y0 = 1.0f - y1;
  const float y3 = y1 - y2;

  // Output layout: [ u : N*4 | v : N*4 | j : N*4 ], all fp32.
  float4* uv = (float4*)out;
  uv[(size_t)p * N + r] = make_float4(y0, y1, y2, y3);
  float2* jj = (float2*)(out + (size_t)8 * N);
  jj[t] = make_float2(l0, l1);
}

extern "C" void kernel_launch(void* const* d_in, const int* in_sizes, int n_in,
                              void* d_out, int out_size, void* d_ws, size_t ws_size,
                              hipStream_t stream) {
  const float* x = (const float*)d_in[0];
  const float* W = (const float*)d_in[1];
  const float* P = (const float*)d_in[2];
  float* out = (float*)d_out;
  const int N = in_sizes[0];          // 8192 rows
  const int threads = 2 * N;          // 2 lanes per row
  dim3 block(64);                     // 1 wave per block -> spread across all 256 CUs
  dim3 grid((threads + 63) / 64);
  hipLaunchKernelGGL(soccer_kernel, grid, block, 0, stream, x, W, P, out, N);
}

// Round 5
// 113.397 us; speedup vs baseline: 1.1904x; 1.0101x over previous
//
#include <hip/hip_runtime.h>

#define TAU_F      0.1f
#define OMT_F      0.9f           // 1 - TAU
#define N_ITERS    1000
#define EPS_F      1e-8f
#define LOG2E_F    1.44269504088896340736f

__device__ __forceinline__ float fexp2(float x){ return __builtin_amdgcn_exp2f(x); }
__device__ __forceinline__ float flog2(float x){ return __builtin_amdgcn_logf(x); }
__device__ __forceinline__ float frcp (float x){ return __builtin_amdgcn_rcpf(x); }

// Swap value with adjacent lane (xor 1) via DPP quad_perm [1,0,3,2].
__device__ __forceinline__ float swap_adj(float x){
  int xi = __builtin_bit_cast(int, x);
  int rr = __builtin_amdgcn_update_dpp(xi, xi, 0xB1, 0xF, 0xF, false);
  return __builtin_bit_cast(float, rr);
}

// Thread t: row r = t>>1, player p = t&1 (0 = u/maximizer, 1 = v/minimizer).
//
// Empirical solo-wave model (R1-R4): time = 4 cyc per VALU/DPP + 12 cyc per
// transcendental, chain depth irrelevant. Minimize weighted count:
//  - State Y = 10*y (kills the 0.1*b1 mul; 0.1 folds into o-coefficients).
//  - Pre-differenced dots: a2 = z~0 - rho*z~2, a3 = z~0 - rho*z~3 as direct
//    2-fma dots over (o1,o2); base = min(a2,a3) = z~0 - rho*max(z~2,z~3);
//    d = iota*(a3-a2) with iota = l1/l0 (= z~2 - z~3 in l1-log2 units).
//  - p2 = exp2(min(d,0) - lg) exactly (= sigma(d), both sign branches).
//  - b1 = rcp(1 + exp2(base - rho*lg)), overflow-safe (exp2->inf -> rcp->0).
// Loop body: 15 ALU + 2 DPP + 5 trans.
__global__ __launch_bounds__(64, 1) void soccer_kernel(
    const float* __restrict__ x, const float* __restrict__ W,
    const float* __restrict__ P, float* __restrict__ out, int N)
{
  const int t = blockIdx.x * 64 + threadIdx.x;
  const int r = t >> 1;
  const int p = t & 1;
  if (r >= N) return;

  const float xv = x[r];
  const float w0 = W[2 * p + 0], w1 = W[2 * p + 1];
  const float l0 = fexp2(xv * (w0 * LOG2E_F)) + EPS_F;
  const float l1 = fexp2(xv * (w1 * LOG2E_F)) + EPS_F;

  const float kappa = l0 * LOG2E_F;   // scale row 0
  const float cin   = l1 * LOG2E_F;   // scale rows 2,3
  const float rho   = l0 / l1;
  const float iota  = l1 / l0;

  // Sign-folded scaled payoff rows {0,2,3} over cols {0,2,3} (Pe row1/col1 = 0),
  // with o0 = 1-o1, o3 = o1-o2 folded: z_c = K_c + C_c1*o1 + C_c2*o2.
  // Then pre-difference: a2/a3 dots, with 0.1 folded for the 10x-scaled o.
  float aK2, aC21, aC22, aK3, aC31, aC32;
  {
    auto m = [&](int c, int k) -> float {
      const float pu = P[c * 4 + k];
      const float pv = -P[k * 4 + c];
      return (p == 0) ? pu : pv;
    };
    const float A00 = kappa * m(0,0), A02 = kappa * m(0,2), A03 = kappa * m(0,3);
    const float A20 = cin   * m(2,0), A22 = cin   * m(2,2), A23 = cin   * m(2,3);
    const float A30 = cin   * m(3,0), A32 = cin   * m(3,2), A33 = cin   * m(3,3);
    const float K0 = A00, C01 = A03 - A00, C02 = A02 - A03;
    const float K2 = A20, C21 = A23 - A20, C22 = A22 - A23;
    const float K3 = A30, C31 = A33 - A30, C32 = A32 - A33;
    aK2  = K0 - rho * K2;
    aC21 = TAU_F * (C01 - rho * C21);
    aC22 = TAU_F * (C02 - rho * C22);
    aK3  = K0 - rho * K3;
    aC31 = TAU_F * (C01 - rho * C31);
    aC32 = TAU_F * (C02 - rho * C32);
  }

  float Y1 = 5.0f, Y2 = 2.5f;   // 10x-scaled y1=0.5, y2=0.25

#pragma unroll 8
  for (int it = 0; it < N_ITERS; ++it) {
    const float o1 = swap_adj(Y1);                     // 10x opponent y1
    const float o2 = swap_adj(Y2);                     // 10x opponent y2

    const float a2 = fmaf(aC22, o2, fmaf(aC21, o1, aK2));  // z~0 - rho*z~2
    const float a3 = fmaf(aC32, o2, fmaf(aC31, o1, aK3));  // z~0 - rho*z~3
    const float base = fminf(a2, a3);                  // z~0 - rho*max(z~2,z~3)
    const float pd = a3 - a2;                          // rho * d
    const float d  = iota * pd;                        // z~2 - z~3 (l1 units)

    const float e   = fexp2(-__builtin_fabsf(d));      // (0,1]; src-mod folds
    const float s   = 1.0f + e;
    const float lg  = flog2(s);                        // log2(1+e)
    const float mn0 = fminf(d, 0.0f);
    const float p2  = fexp2(mn0 - lg);                 // = sigma(d), exact both signs

    const float t2 = fmaf(-rho, lg, base);             // z~0 - rho*lse~
    const float e2 = fexp2(t2);
    const float b1 = frcp(1.0f + e2);                  // rcp(inf)=0: safe

    const float m2 = OMT_F * Y2;
    Y1 = fmaf(OMT_F, Y1, b1);                          // Y' = 0.9 Y + b (10x scale)
    Y2 = fmaf(b1, p2, m2);
  }

  const float y1 = TAU_F * Y1;   // /10
  const float y2 = TAU_F * Y2;
  const float y0 = 1.0f - y1;
  const float y3 = y1 - y2;

  // Output layout: [ u : N*4 | v : N*4 | j : N*4 ], all fp32.
  float4* uv = (float4*)out;
  uv[(size_t)p * N + r] = make_float4(y0, y1, y2, y3);
  float2* jj = (float2*)(out + (size_t)8 * N);
  jj[t] = make_float2(l0, l1);
}

extern "C" void kernel_launch(void* const* d_in, const int* in_sizes, int n_in,
                              void* d_out, int out_size, void* d_ws, size_t ws_size,
                              hipStream_t stream) {
  const float* x = (const float*)d_in[0];
  const float* W = (const float*)d_in[1];
  const float* P = (const float*)d_in[2];
  float* out = (float*)d_out;
  const int N = in_sizes[0];          // 8192 rows
  const int threads = 2 * N;          // 2 lanes per row
  dim3 block(64);                     // 1 wave per block -> spread across all 256 CUs
  dim3 grid((threads + 63) / 64);
  hipLaunchKernelGGL(soccer_kernel, grid, block, 0, stream, x, W, P, out, N);
}

// Round 6
// 106.549 us; speedup vs baseline: 1.2670x; 1.0643x over previous
//
#include <hip/hip_runtime.h>

#define TAU_F      0.1f
#define OMT_F      0.9f           // 1 - TAU
#define N_ITERS    1000
#define EPS_F      1e-8f
#define LOG2E_F    1.44269504088896340736f

__device__ __forceinline__ float fexp2(float x){ return __builtin_amdgcn_exp2f(x); }
__device__ __forceinline__ float flog2(float x){ return __builtin_amdgcn_logf(x); }
__device__ __forceinline__ float frcp (float x){ return __builtin_amdgcn_rcpf(x); }

// Swap value with adjacent lane (xor 1) via DPP quad_perm [1,0,3,2].
__device__ __forceinline__ float swap_adj(float x){
  int xi = __builtin_bit_cast(int, x);
  int rr = __builtin_amdgcn_update_dpp(xi, xi, 0xB1, 0xF, 0xF, false);
  return __builtin_bit_cast(float, rr);
}

// Thread t: row r = t>>1, player p = t&1 (0 = u/maximizer, 1 = v/minimizer).
//
// Model (fit R1-R5): time/iter = max(issue ~4cyc/instr, chain: ALU~5, trans~25,
// DPP~7). R5 was chain-bound at ~147 cyc. This round carries the three
// pre-differenced dots (a2, a3, d) as state:
//   a' = fma(b1o, w, 0.9*a + 0.1*aK),  w = fma(aC2, p2o, aC1)
// p2o is swapped ~55 cyc before b1o, so w and the 0.9-blend are off-chain.
// Critical cycle: b1 -> DPP -> fma(d') -> exp2 -> add -> log2 -> fma(t2)
//                 -> exp2 -> add -> rcp  (~127 cyc; issue ~25 instr ~120).
// d carries iota = l1/l0 pre-folded (no sub/mul on chain).
__global__ __launch_bounds__(64, 1) void soccer_kernel(
    const float* __restrict__ x, const float* __restrict__ W,
    const float* __restrict__ P, float* __restrict__ out, int N)
{
  const int t = blockIdx.x * 64 + threadIdx.x;
  const int r = t >> 1;
  const int p = t & 1;
  if (r >= N) return;

  const float xv = x[r];
  const float w0 = W[2 * p + 0], w1 = W[2 * p + 1];
  const float l0 = fexp2(xv * (w0 * LOG2E_F)) + EPS_F;
  const float l1 = fexp2(xv * (w1 * LOG2E_F)) + EPS_F;

  const float kappa = l0 * LOG2E_F;
  const float cin   = l1 * LOG2E_F;
  const float rho   = l0 / l1;
  const float iota  = l1 / l0;

  // Pre-differenced dot coefficients (cols folded by o0=1-o1, o3=o1-o2;
  // TAU folded for the 10x-scaled opponent state; d-row iota-prescaled).
  float aK2, aC21, aC22, aK3, aC31, aC32, dKp, dC1p, dC2p;
  {
    auto m = [&](int c, int k) -> float {
      const float pu = P[c * 4 + k];
      const float pv = -P[k * 4 + c];
      return (p == 0) ? pu : pv;
    };
    const float A00 = kappa * m(0,0), A02 = kappa * m(0,2), A03 = kappa * m(0,3);
    const float A20 = cin   * m(2,0), A22 = cin   * m(2,2), A23 = cin   * m(2,3);
    const float A30 = cin   * m(3,0), A32 = cin   * m(3,2), A33 = cin   * m(3,3);
    const float K0 = A00, C01 = A03 - A00, C02 = A02 - A03;
    const float K2 = A20, C21 = A23 - A20, C22 = A22 - A23;
    const float K3 = A30, C31 = A33 - A30, C32 = A32 - A33;
    aK2  = K0 - rho * K2;
    aC21 = TAU_F * (C01 - rho * C21);
    aC22 = TAU_F * (C02 - rho * C22);
    aK3  = K0 - rho * K3;
    aC31 = TAU_F * (C01 - rho * C31);
    aC32 = TAU_F * (C02 - rho * C32);
    dKp  = iota * (aK3 - aK2);
    dC1p = iota * (aC31 - aC21);
    dC2p = iota * (aC32 - aC22);
  }
  const float cK2 = TAU_F * aK2;   // 0.1*aK blend constants
  const float cK3 = TAU_F * aK3;
  const float cKd = TAU_F * dKp;

  // Initial dots at o1=5, o2=2.5 (10x-scaled init strategy, same both lanes).
  float a2 = aK2 + 5.0f * aC21 + 2.5f * aC22;
  float a3 = aK3 + 5.0f * aC31 + 2.5f * aC32;
  float d  = dKp + 5.0f * dC1p + 2.5f * dC2p;

  float Y1 = 5.0f, Y2 = 2.5f;   // 10x-scaled own strategy (output only)

#pragma unroll 8
  for (int it = 0; it < N_ITERS; ++it) {
    // ---- critical chain: d -> e -> lg -> t2 -> e2 -> b1 ----
    const float e    = fexp2(-__builtin_fabsf(d));     // (0,1]
    const float s    = 1.0f + e;
    const float lg   = flog2(s);                       // log2(1+e)
    const float base = fminf(a2, a3);                  // off-chain (slack)
    const float t2   = fmaf(-rho, lg, base);
    const float e2   = fexp2(t2);
    const float b1   = frcp(1.0f + e2);                // rcp(inf)=0: safe

    // ---- p2 = sigma(d) = exp2(min(d,0) - lg); ready ~55cyc before b1 ----
    const float mn0 = fminf(d, 0.0f);
    const float p2  = fexp2(mn0 - lg);

    // ---- early swap + off-chain prep ----
    const float p2o = swap_adj(p2);
    const float w2  = fmaf(aC22, p2o, aC21);
    const float w3  = fmaf(aC32, p2o, aC31);
    const float wd  = fmaf(dC2p, p2o, dC1p);
    const float n2  = fmaf(OMT_F, a2, cK2);
    const float n3  = fmaf(OMT_F, a3, cK3);
    const float nd  = fmaf(OMT_F, d,  cKd);

    // ---- own-strategy accumulators (output only, off-chain) ----
    Y1 = fmaf(OMT_F, Y1, b1);
    const float q = b1 * p2;
    Y2 = fmaf(OMT_F, Y2, q);

    // ---- the one on-chain hop across lanes ----
    const float b1o = swap_adj(b1);
    d  = fmaf(b1o, wd, nd);
    a2 = fmaf(b1o, w2, n2);
    a3 = fmaf(b1o, w3, n3);
  }

  const float y1 = TAU_F * Y1;   // /10
  const float y2 = TAU_F * Y2;
  const float y0 = 1.0f - y1;
  const float y3 = y1 - y2;

  // Output layout: [ u : N*4 | v : N*4 | j : N*4 ], all fp32.
  float4* uv = (float4*)out;
  uv[(size_t)p * N + r] = make_float4(y0, y1, y2, y3);
  float2* jj = (float2*)(out + (size_t)8 * N);
  jj[t] = make_float2(l0, l1);
}

extern "C" void kernel_launch(void* const* d_in, const int* in_sizes, int n_in,
                              void* d_out, int out_size, void* d_ws, size_t ws_size,
                              hipStream_t stream) {
  const float* x = (const float*)d_in[0];
  const float* W = (const float*)d_in[1];
  const float* P = (const float*)d_in[2];
  float* out = (float*)d_out;
  const int N = in_sizes[0];          // 8192 rows
  const int threads = 2 * N;          // 2 lanes per row
  dim3 block(64);                     // 1 wave per block -> spread across all 256 CUs
  dim3 grid((threads + 63) / 64);
  hipLaunchKernelGGL(soccer_kernel, grid, block, 0, stream, x, W, P, out, N);
}